// Round 8
// baseline (976.689 us; speedup 1.0000x reference)
//
#include <hip/hip_runtime.h>

#define S_LEN 2048
#define H_DIM 1024
#define NHEAD 8
#define D_HEAD 128
#define KSPLIT 4
#define KV_PER (S_LEN / KSPLIT)  // 512 kv positions per split

typedef __bf16 bf16x8 __attribute__((ext_vector_type(8)));
typedef float floatx4 __attribute__((ext_vector_type(4)));

__device__ __forceinline__ float b2f(unsigned short u) {
    union { unsigned int i; float f; } v;
    v.i = ((unsigned int)u) << 16;
    return v.f;
}
__device__ __forceinline__ unsigned short f2b(float f) {
    union { float f; unsigned int i; } v;
    v.f = f;
    return (unsigned short)((v.i + 0x7fffu + ((v.i >> 16) & 1u)) >> 16);
}

// async global->LDS DMA, 16 B per lane; lds dst = wave-uniform base + lane*16
__device__ __forceinline__ void dma16(void* lds, const void* g) {
    __builtin_amdgcn_global_load_lds(
        (const __attribute__((address_space(1))) void*)g,
        (__attribute__((address_space(3))) void*)lds, 16, 0, 0);
}

// ---------------- positional encoding + input add (fp32 in -> fp32 + bf16 out) ----------------
__global__ __launch_bounds__(256) void posenc_kernel(
    const float* __restrict__ in, float* __restrict__ xf,
    unsigned short* __restrict__ xb)
{
    int g = blockIdx.x * 256 + threadIdx.x;
    int s = g >> 10;
    int h = g & 1023;
    float dv = powf(10000.0f, -(float)h * (1.0f / 512.0f));
    float ang = (float)s * dv;
    float pe = (h & 1) ? cosf(ang) : sinf(ang);
    float x = in[g] + pe;
    xf[g] = x;
    xb[g] = f2b(x);
}

// ---------------- fp32 -> bf16 transpose (per head, [R,C] -> [C,R]) ----------------
__global__ __launch_bounds__(256) void transpose_f2b(
    const float* __restrict__ in, unsigned short* __restrict__ out, int R, int C)
{
    __shared__ unsigned short tile[32][33];
    const float* ih = in + (size_t)blockIdx.z * R * C;
    unsigned short* oh = out + (size_t)blockIdx.z * R * C;
    int r0 = blockIdx.y * 32, c0 = blockIdx.x * 32;
    int tx = threadIdx.x, ty = threadIdx.y;
    for (int i = ty; i < 32; i += 8)
        tile[i][tx] = f2b(ih[(size_t)(r0 + i) * C + c0 + tx]);
    __syncthreads();
    for (int i = ty; i < 32; i += 8)
        oh[(size_t)(c0 + i) * R + r0 + tx] = tile[tx][i];
}

// ---------------- GEMM: C[M,N] = A[M,K] @ Bt[N,K]^T + bias ----------------
// 64x64 tile, BK=64, global_load_lds staging into XOR-swizzled unpadded tiles,
// double-buffered LDS: DMA of slab k+1 overlaps MFMAs on slab k. 512 blocks.
// MODE 0: bf16 out [M,N]; MODE 1: bf16 out transposed [N, ldt]; MODE 2: f32 out [M,N]
template <int MODE, bool RELU>
__global__ __launch_bounds__(256, 4) void gemm_bt(
    const unsigned short* __restrict__ A, const unsigned short* __restrict__ Bt,
    const float* __restrict__ bias, float* __restrict__ Cf,
    unsigned short* __restrict__ Cb, int M, int N, int K, int ldt)
{
    __shared__ __align__(16) unsigned short sA[2][64 * 64];
    __shared__ __align__(16) unsigned short sB[2][64 * 64];
    const int tid = threadIdx.x;
    const int wave = tid >> 6, lane = tid & 63;
    const int quad = lane >> 4, l16 = lane & 15;
    const int i0 = blockIdx.y * 64, j0 = blockIdx.x * 64;
    const int wm = (wave >> 1) * 32, wn = (wave & 1) * 32;

    const int srow = lane >> 3;                       // 0..7 within wave group
    const int schunk = (lane & 7) ^ (srow & 7);       // global chunk to fetch (XOR swizzle)
    const unsigned short* Ap0 = A + (size_t)(i0 + wave * 8 + srow) * K + schunk * 8;
    const unsigned short* Ap1 = A + (size_t)(i0 + 32 + wave * 8 + srow) * K + schunk * 8;
    const unsigned short* Bp0 = Bt + (size_t)(j0 + wave * 8 + srow) * K + schunk * 8;
    const unsigned short* Bp1 = Bt + (size_t)(j0 + 32 + wave * 8 + srow) * K + schunk * 8;
    const int ld0 = (wave * 8) * 64, ld1 = (32 + wave * 8) * 64;

    floatx4 z4 = {0.f, 0.f, 0.f, 0.f};
    floatx4 acc[2][2];
#pragma unroll
    for (int i = 0; i < 2; i++)
#pragma unroll
        for (int j = 0; j < 2; j++) acc[i][j] = z4;

    dma16(sA[0] + ld0, Ap0);
    dma16(sA[0] + ld1, Ap1);
    dma16(sB[0] + ld0, Bp0);
    dma16(sB[0] + ld1, Bp1);
    __syncthreads();

    int buf = 0;
    for (int k0 = 0; k0 < K; k0 += 64) {
        if (k0 + 64 < K) {
            dma16(sA[buf ^ 1] + ld0, Ap0 + k0 + 64);
            dma16(sA[buf ^ 1] + ld1, Ap1 + k0 + 64);
            dma16(sB[buf ^ 1] + ld0, Bp0 + k0 + 64);
            dma16(sB[buf ^ 1] + ld1, Bp1 + k0 + 64);
        }
        const unsigned short* cA = sA[buf];
        const unsigned short* cB = sB[buf];
#pragma unroll
        for (int kh = 0; kh < 2; kh++) {
            bf16x8 af[2], bfr[2];
#pragma unroll
            for (int mi = 0; mi < 2; mi++) {
                int row = wm + mi * 16 + l16;
                int p = (kh * 4 + quad) ^ (l16 & 7);
                af[mi] = *(const bf16x8*)(cA + row * 64 + p * 8);
            }
#pragma unroll
            for (int ni = 0; ni < 2; ni++) {
                int row = wn + ni * 16 + l16;
                int p = (kh * 4 + quad) ^ (l16 & 7);
                bfr[ni] = *(const bf16x8*)(cB + row * 64 + p * 8);
            }
#pragma unroll
            for (int mi = 0; mi < 2; mi++)
#pragma unroll
                for (int ni = 0; ni < 2; ni++)
                    acc[mi][ni] = __builtin_amdgcn_mfma_f32_16x16x32_bf16(
                        af[mi], bfr[ni], acc[mi][ni], 0, 0, 0);
        }
        __syncthreads();
        buf ^= 1;
    }

#pragma unroll
    for (int mi = 0; mi < 2; mi++) {
#pragma unroll
        for (int ni = 0; ni < 2; ni++) {
            const int col = j0 + wn + ni * 16 + l16;
            const float bval = bias[col];
#pragma unroll
            for (int r = 0; r < 4; r++) {
                const int row_o = i0 + wm + mi * 16 + quad * 4 + r;  // C/D: row=quad*4+reg
                float v = acc[mi][ni][r] + bval;
                if (RELU) v = fmaxf(v, 0.0f);
                if (MODE == 0) Cb[(size_t)row_o * N + col] = f2b(v);
                else if (MODE == 1) Cb[(size_t)col * ldt + row_o] = f2b(v);
                else Cf[(size_t)row_o * N + col] = v;
            }
        }
    }
}

// ---------------- flash attention: 1-barrier pipelined K-loop ----------------
// block = (64 q rows, head, split). V double-buffered in LDS: DMA for tile i+1
// issued at TOP of tile i, drained by the single loop-end barrier -> fully
// overlapped with QK+exp+P+PV. K fragments read DIRECT from global (L2-resident,
// B-frag rows coalesce as 16x64B segments) -> no sK, no second barrier.
// LDS 41.2 KB -> 3 blocks/CU; (256,3) targets <=170 VGPR (est ~140, no spill).
__global__ __launch_bounds__(256, 3) void flash_attn(
    const unsigned short* __restrict__ Qg, const unsigned short* __restrict__ Kg,
    const unsigned short* __restrict__ Vt, unsigned short* __restrict__ Op,
    float* __restrict__ Lp)
{
    __shared__ __align__(16) unsigned short sV[2][128 * 64];  // [d][t], chunk swz key row&7
    __shared__ __align__(16) unsigned short sP[4 * 16 * 72];  // wave-private P

    const int tid = threadIdx.x;
    const int wave = tid >> 6, lane = tid & 63;
    const int quad = lane >> 4, l16 = lane & 15;
    const int head = blockIdx.y;
    const int q0 = blockIdx.x * 64;
    const int split = blockIdx.z;
    const int h0 = head * D_HEAD;

    // Q fragments direct from global (loop-invariant)
    bf16x8 aq[4];
    const int qrow = q0 + wave * 16 + l16;
#pragma unroll
    for (int ks = 0; ks < 4; ks++)
        aq[ks] = *(const bf16x8*)(Qg + (size_t)qrow * H_DIM + h0 + ks * 32 + quad * 8);

    unsigned short* myP = sP + wave * (16 * 72);

    // V staging: 8 lanes/row, 8 rows/instr/wave, 4 instrs
    const int v_r = wave * 8 + (lane >> 3);
    const int v_c = (lane & 7) ^ (v_r & 7);

    const unsigned short* Kbase = Kg + h0;
    const unsigned short* Vbase = Vt + (size_t)h0 * S_LEN;
    const int kt0 = split * KV_PER;

    floatx4 z4 = {0.f, 0.f, 0.f, 0.f};
    floatx4 o[8];
#pragma unroll
    for (int i = 0; i < 8; i++) o[i] = z4;
    float l_r[4] = {0.f, 0.f, 0.f, 0.f};

    // prologue: stage V(0) into buf 0
#pragma unroll
    for (int it = 0; it < 4; it++)
        dma16(sV[0] + (wave * 8 + it * 32) * 64,
              Vbase + (size_t)(v_r + it * 32) * S_LEN + kt0 + v_c * 8);
    __syncthreads();

    int buf = 0;
    for (int it0 = 0; it0 < KV_PER; it0 += 64) {
        const int t0 = kt0 + it0;
        // stage V(i+1) into the other buffer; drained by the loop-end barrier,
        // overlapped with all of this tile's compute
        if (it0 + 64 < KV_PER) {
            const int nt = t0 + 64;
#pragma unroll
            for (int it = 0; it < 4; it++)
                dma16(sV[buf ^ 1] + (wave * 8 + it * 32) * 64,
                      Vbase + (size_t)(v_r + it * 32) * S_LEN + nt + v_c * 8);
        }

        // scores S[16 q][64 t] = Q K^T, K frags direct from global (L2)
        floatx4 sc[4];
#pragma unroll
        for (int ni = 0; ni < 4; ni++) {
            bf16x8 bkf[4];
#pragma unroll
            for (int ks = 0; ks < 4; ks++)
                bkf[ks] = *(const bf16x8*)(Kbase +
                    (size_t)(t0 + ni * 16 + l16) * H_DIM + ks * 32 + quad * 8);
            sc[ni] = z4;
#pragma unroll
            for (int ks = 0; ks < 4; ks++)
                sc[ni] = __builtin_amdgcn_mfma_f32_16x16x32_bf16(aq[ks], bkf[ks], sc[ni], 0, 0, 0);
        }

        // exp without max subtraction (scores provably small); per-lane l partial
#pragma unroll
        for (int ni = 0; ni < 4; ni++)
#pragma unroll
            for (int r = 0; r < 4; r++) {
                float p = __expf(sc[ni][r] * 0.03125f);  // 1/sqrt(H)=1/32
                sc[ni][r] = p;
                l_r[r] += p;
            }

        // P: C-layout -> wave-private padded LDS -> A-layout (no barrier)
#pragma unroll
        for (int ni = 0; ni < 4; ni++)
#pragma unroll
            for (int r = 0; r < 4; r++) {
                int prow = quad * 4 + r;
                myP[prow * 72 + ((ni * 16 + l16) ^ ((prow & 8) << 1))] = f2b(sc[ni][r]);
            }
        bf16x8 ap[2];
#pragma unroll
        for (int ks = 0; ks < 2; ks++)
            ap[ks] = *(const bf16x8*)(myP + l16 * 72 + ((ks * 32 + quad * 8) ^ ((l16 & 8) << 1)));

        // PV from current V buffer
#pragma unroll
        for (int ni = 0; ni < 8; ni++) {
#pragma unroll
            for (int ks = 0; ks < 2; ks++) {
                int p = (ks * 4 + quad) ^ (l16 & 7);
                bf16x8 bv = *(const bf16x8*)(sV[buf] + (ni * 16 + l16) * 64 + p * 8);
                o[ni] = __builtin_amdgcn_mfma_f32_16x16x32_bf16(ap[ks], bv, o[ni], 0, 0, 0);
            }
        }

        __syncthreads();  // single barrier: drains V-DMA, fences PV reads of sV[buf]
        buf ^= 1;
    }

    // one-time l reduction across the 16-lane groups
#pragma unroll
    for (int r = 0; r < 4; r++)
#pragma unroll
        for (int off = 1; off < 16; off <<= 1)
            l_r[r] += __shfl_xor(l_r[r], off, 64);

#pragma unroll
    for (int r = 0; r < 4; r++) {
        float inv = 1.0f / l_r[r];
        int row = q0 + wave * 16 + quad * 4 + r;
#pragma unroll
        for (int ni = 0; ni < 8; ni++)
            Op[((size_t)split * S_LEN + row) * H_DIM + h0 + ni * 16 + l16] =
                f2b(o[ni][r] * inv);
        if (l16 == 0)
            Lp[(split * NHEAD + head) * S_LEN + row] = l_r[r];
    }
}

// ---------------- merge KV-split partials + residual add + LayerNorm ----------------
__global__ __launch_bounds__(256) void merge_add_layernorm(
    const float* __restrict__ t, const unsigned short* __restrict__ Op,
    const float* __restrict__ Lp,
    float* __restrict__ of, unsigned short* __restrict__ ob)
{
    __shared__ float red[8];
    const int row = blockIdx.x, tid = threadIdx.x;
    const int head = tid >> 5;  // 32 threads per head (128 dims / 4)
    const size_t base = (size_t)row * H_DIM + tid * 4;

    float l_s[KSPLIT];
    ushort4 os[KSPLIT];
#pragma unroll
    for (int sp = 0; sp < KSPLIT; sp++) {
        os[sp] = *(const ushort4*)(Op + ((size_t)sp * S_LEN + row) * H_DIM + tid * 4);
        l_s[sp] = Lp[(sp * NHEAD + head) * S_LEN + row];
    }
    float W = 0.f, a0 = 0.f, a1 = 0.f, a2 = 0.f, a3 = 0.f;
#pragma unroll
    for (int sp = 0; sp < KSPLIT; sp++) {
        float w = l_s[sp];  // no-max softmax: weight is the raw partial sum
        W += w;
        a0 += w * b2f(os[sp].x);
        a1 += w * b2f(os[sp].y);
        a2 += w * b2f(os[sp].z);
        a3 += w * b2f(os[sp].w);
    }
    float inv = 1.0f / W;
    float4 x = *(const float4*)(t + base);
    float v0 = x.x + a0 * inv, v1 = x.y + a1 * inv;
    float v2 = x.z + a2 * inv, v3 = x.w + a3 * inv;

    float s = v0 + v1 + v2 + v3;
    float q = v0 * v0 + v1 * v1 + v2 * v2 + v3 * v3;
#pragma unroll
    for (int off = 32; off >= 1; off >>= 1) {
        s += __shfl_xor(s, off, 64);
        q += __shfl_xor(q, off, 64);
    }
    if ((tid & 63) == 0) { red[tid >> 6] = s; red[4 + (tid >> 6)] = q; }
    __syncthreads();
    s = red[0] + red[1] + red[2] + red[3];
    q = red[4] + red[5] + red[6] + red[7];
    const float mean = s * (1.0f / (float)H_DIM);
    const float var = q * (1.0f / (float)H_DIM) - mean * mean;
    const float rstd = rsqrtf(var + 1e-5f);
    float o0 = (v0 - mean) * rstd, o1 = (v1 - mean) * rstd;
    float o2 = (v2 - mean) * rstd, o3 = (v3 - mean) * rstd;
    *(float4*)(of + base) = make_float4(o0, o1, o2, o3);
    *(ushort4*)(ob + base) = make_ushort4(f2b(o0), f2b(o1), f2b(o2), f2b(o3));
}

// ---------------- fused residual add + LayerNorm (fp32 in -> fp32 + bf16 out) ----------------
__global__ __launch_bounds__(256) void add_layernorm(
    const float* __restrict__ a, const float* __restrict__ b,
    float* __restrict__ of, unsigned short* __restrict__ ob)
{
    __shared__ float red[8];
    const int row = blockIdx.x, tid = threadIdx.x;
    const size_t base = (size_t)row * H_DIM + tid * 4;
    float4 x = *(const float4*)(a + base);
    float4 y = *(const float4*)(b + base);
    float v0 = x.x + y.x, v1 = x.y + y.y, v2 = x.z + y.z, v3 = x.w + y.w;
    float s = v0 + v1 + v2 + v3;
    float q = v0 * v0 + v1 * v1 + v2 * v2 + v3 * v3;
#pragma unroll
    for (int off = 32; off >= 1; off >>= 1) {
        s += __shfl_xor(s, off, 64);
        q += __shfl_xor(q, off, 64);
    }
    if ((tid & 63) == 0) { red[tid >> 6] = s; red[4 + (tid >> 6)] = q; }
    __syncthreads();
    s = red[0] + red[1] + red[2] + red[3];
    q = red[4] + red[5] + red[6] + red[7];
    const float mean = s * (1.0f / (float)H_DIM);
    const float var = q * (1.0f / (float)H_DIM) - mean * mean;
    const float rstd = rsqrtf(var + 1e-5f);
    float o0 = (v0 - mean) * rstd, o1 = (v1 - mean) * rstd;
    float o2 = (v2 - mean) * rstd, o3 = (v3 - mean) * rstd;
    *(float4*)(of + base) = make_float4(o0, o1, o2, o3);
    *(ushort4*)(ob + base) = make_ushort4(f2b(o0), f2b(o1), f2b(o2), f2b(o3));
}

extern "C" void kernel_launch(void* const* d_in, const int* in_sizes, int n_in,
                              void* d_out, int out_size, void* d_ws, size_t ws_size,
                              hipStream_t stream)
{
    (void)in_sizes; (void)n_in; (void)out_size; (void)ws_size;
    const float* in = (const float*)d_in[0];
    const float* Wq = (const float*)d_in[1];
    const float* bq = (const float*)d_in[2];
    const float* Wk = (const float*)d_in[3];
    const float* bk = (const float*)d_in[4];
    const float* Wv = (const float*)d_in[5];
    const float* bv = (const float*)d_in[6];
    const float* W1 = (const float*)d_in[7];
    const float* b1 = (const float*)d_in[8];
    const float* W2 = (const float*)d_in[9];
    const float* b2 = (const float*)d_in[10];

    char* ws = (char*)d_ws;
    const size_t MB = 1024 * 1024;
    float* t_f32 = (float*)(ws + 0 * MB);                    // 8 MB
    float* cf_f32 = (float*)(ws + 8 * MB);                   // 8 MB (ff2)
    unsigned short* t_b = (unsigned short*)(ws + 16 * MB);   // 4 MB
    unsigned short* K_b = (unsigned short*)(ws + 20 * MB);   // 4 MB
    unsigned short* Vt_b = (unsigned short*)(ws + 24 * MB);  // 4 MB, [NH,D,S]
    unsigned short* Q_b = (unsigned short*)(ws + 28 * MB);   // 4 MB (also ff1)
    unsigned short* WqT = (unsigned short*)(ws + 32 * MB);   // 2 MB each, [N,K]
    unsigned short* WkT = (unsigned short*)(ws + 34 * MB);
    unsigned short* WvT = (unsigned short*)(ws + 36 * MB);
    unsigned short* W1T = (unsigned short*)(ws + 38 * MB);
    unsigned short* W2T = (unsigned short*)(ws + 40 * MB);
    unsigned short* Op = (unsigned short*)(ws + 42 * MB);    // 16 MB [split][S][H] bf16
    float* Lp = (float*)(ws + 58 * MB);                      // 256 KB [split][NH][S]

    dim3 tb(32, 8);
    transpose_f2b<<<dim3(4, 32, 8), tb, 0, stream>>>(Wq, WqT, H_DIM, D_HEAD);
    transpose_f2b<<<dim3(4, 32, 8), tb, 0, stream>>>(Wk, WkT, H_DIM, D_HEAD);
    transpose_f2b<<<dim3(4, 32, 8), tb, 0, stream>>>(Wv, WvT, H_DIM, D_HEAD);
    transpose_f2b<<<dim3(32, 32, 1), tb, 0, stream>>>(W1, W1T, H_DIM, H_DIM);
    transpose_f2b<<<dim3(32, 32, 1), tb, 0, stream>>>(W2, W2T, H_DIM, H_DIM);

    posenc_kernel<<<(S_LEN * H_DIM) / 256, 256, 0, stream>>>(in, t_f32, t_b);

    dim3 gg(H_DIM / 64, S_LEN / 64);  // 16 x 32 = 512 blocks
    gemm_bt<0, false><<<gg, 256, 0, stream>>>(t_b, WkT, bk, nullptr, K_b, S_LEN, H_DIM, H_DIM, 0);
    gemm_bt<1, false><<<gg, 256, 0, stream>>>(t_b, WvT, bv, nullptr, Vt_b, S_LEN, H_DIM, H_DIM, S_LEN);

    for (int layer = 0; layer < 6; layer++) {
        gemm_bt<0, false><<<gg, 256, 0, stream>>>(t_b, WqT, bq, nullptr, Q_b, S_LEN, H_DIM, H_DIM, 0);
        flash_attn<<<dim3(S_LEN / 64, NHEAD, KSPLIT), 256, 0, stream>>>(Q_b, K_b, Vt_b, Op, Lp);
        merge_add_layernorm<<<S_LEN, 256, 0, stream>>>(t_f32, Op, Lp, t_f32, t_b);
        gemm_bt<0, true><<<gg, 256, 0, stream>>>(t_b, W1T, b1, nullptr, Q_b, S_LEN, H_DIM, H_DIM, 0);
        gemm_bt<2, false><<<gg, 256, 0, stream>>>(Q_b, W2T, b2, cf_f32, nullptr, S_LEN, H_DIM, H_DIM, 0);
        float* of = (layer == 5) ? (float*)d_out : t_f32;
        add_layernorm<<<S_LEN, 256, 0, stream>>>(t_f32, cf_f32, of, t_b);
    }
}

// Round 9
// 639.532 us; speedup vs baseline: 1.5272x; 1.5272x over previous
//
#include <hip/hip_runtime.h>

#define S_LEN 2048
#define H_DIM 1024
#define NHEAD 8
#define D_HEAD 128
#define KSPLIT 4
#define KV_PER (S_LEN / KSPLIT)  // 512 kv positions per split

typedef __bf16 bf16x8 __attribute__((ext_vector_type(8)));
typedef float floatx4 __attribute__((ext_vector_type(4)));

__device__ __forceinline__ float b2f(unsigned short u) {
    union { unsigned int i; float f; } v;
    v.i = ((unsigned int)u) << 16;
    return v.f;
}
__device__ __forceinline__ unsigned short f2b(float f) {
    union { float f; unsigned int i; } v;
    v.f = f;
    return (unsigned short)((v.i + 0x7fffu + ((v.i >> 16) & 1u)) >> 16);
}

// async global->LDS DMA, 16 B per lane; lds dst = wave-uniform base + lane*16
__device__ __forceinline__ void dma16(void* lds, const void* g) {
    __builtin_amdgcn_global_load_lds(
        (const __attribute__((address_space(1))) void*)g,
        (__attribute__((address_space(3))) void*)lds, 16, 0, 0);
}

// ---------------- positional encoding + input add (fp32 in -> fp32 + bf16 out) ----------------
__global__ __launch_bounds__(256) void posenc_kernel(
    const float* __restrict__ in, float* __restrict__ xf,
    unsigned short* __restrict__ xb)
{
    int g = blockIdx.x * 256 + threadIdx.x;
    int s = g >> 10;
    int h = g & 1023;
    float dv = powf(10000.0f, -(float)h * (1.0f / 512.0f));
    float ang = (float)s * dv;
    float pe = (h & 1) ? cosf(ang) : sinf(ang);
    float x = in[g] + pe;
    xf[g] = x;
    xb[g] = f2b(x);
}

// ---------------- fp32 -> bf16 transpose (per head, [R,C] -> [C,R]) ----------------
__global__ __launch_bounds__(256) void transpose_f2b(
    const float* __restrict__ in, unsigned short* __restrict__ out, int R, int C)
{
    __shared__ unsigned short tile[32][33];
    const float* ih = in + (size_t)blockIdx.z * R * C;
    unsigned short* oh = out + (size_t)blockIdx.z * R * C;
    int r0 = blockIdx.y * 32, c0 = blockIdx.x * 32;
    int tx = threadIdx.x, ty = threadIdx.y;
    for (int i = ty; i < 32; i += 8)
        tile[i][tx] = f2b(ih[(size_t)(r0 + i) * C + c0 + tx]);
    __syncthreads();
    for (int i = ty; i < 32; i += 8)
        oh[(size_t)(c0 + i) * R + r0 + tx] = tile[tx][i];
}

// ---------------- GEMM: C[M,N] = A[M,K] @ Bt[N,K]^T + bias ----------------
// 64x64 tile, BK=64, global_load_lds staging into XOR-swizzled unpadded tiles,
// double-buffered LDS: DMA of slab k+1 overlaps MFMAs on slab k. 512 blocks.
// MODE 0: bf16 out [M,N]; MODE 1: bf16 out transposed [N, ldt]; MODE 2: f32 out [M,N]
template <int MODE, bool RELU>
__global__ __launch_bounds__(256, 4) void gemm_bt(
    const unsigned short* __restrict__ A, const unsigned short* __restrict__ Bt,
    const float* __restrict__ bias, float* __restrict__ Cf,
    unsigned short* __restrict__ Cb, int M, int N, int K, int ldt)
{
    __shared__ __align__(16) unsigned short sA[2][64 * 64];
    __shared__ __align__(16) unsigned short sB[2][64 * 64];
    const int tid = threadIdx.x;
    const int wave = tid >> 6, lane = tid & 63;
    const int quad = lane >> 4, l16 = lane & 15;
    const int i0 = blockIdx.y * 64, j0 = blockIdx.x * 64;
    const int wm = (wave >> 1) * 32, wn = (wave & 1) * 32;

    const int srow = lane >> 3;                       // 0..7 within wave group
    const int schunk = (lane & 7) ^ (srow & 7);       // global chunk to fetch (XOR swizzle)
    const unsigned short* Ap0 = A + (size_t)(i0 + wave * 8 + srow) * K + schunk * 8;
    const unsigned short* Ap1 = A + (size_t)(i0 + 32 + wave * 8 + srow) * K + schunk * 8;
    const unsigned short* Bp0 = Bt + (size_t)(j0 + wave * 8 + srow) * K + schunk * 8;
    const unsigned short* Bp1 = Bt + (size_t)(j0 + 32 + wave * 8 + srow) * K + schunk * 8;
    const int ld0 = (wave * 8) * 64, ld1 = (32 + wave * 8) * 64;

    floatx4 z4 = {0.f, 0.f, 0.f, 0.f};
    floatx4 acc[2][2];
#pragma unroll
    for (int i = 0; i < 2; i++)
#pragma unroll
        for (int j = 0; j < 2; j++) acc[i][j] = z4;

    dma16(sA[0] + ld0, Ap0);
    dma16(sA[0] + ld1, Ap1);
    dma16(sB[0] + ld0, Bp0);
    dma16(sB[0] + ld1, Bp1);
    __syncthreads();

    int buf = 0;
    for (int k0 = 0; k0 < K; k0 += 64) {
        if (k0 + 64 < K) {
            dma16(sA[buf ^ 1] + ld0, Ap0 + k0 + 64);
            dma16(sA[buf ^ 1] + ld1, Ap1 + k0 + 64);
            dma16(sB[buf ^ 1] + ld0, Bp0 + k0 + 64);
            dma16(sB[buf ^ 1] + ld1, Bp1 + k0 + 64);
        }
        const unsigned short* cA = sA[buf];
        const unsigned short* cB = sB[buf];
#pragma unroll
        for (int kh = 0; kh < 2; kh++) {
            bf16x8 af[2], bfr[2];
#pragma unroll
            for (int mi = 0; mi < 2; mi++) {
                int row = wm + mi * 16 + l16;
                int p = (kh * 4 + quad) ^ (l16 & 7);
                af[mi] = *(const bf16x8*)(cA + row * 64 + p * 8);
            }
#pragma unroll
            for (int ni = 0; ni < 2; ni++) {
                int row = wn + ni * 16 + l16;
                int p = (kh * 4 + quad) ^ (l16 & 7);
                bfr[ni] = *(const bf16x8*)(cB + row * 64 + p * 8);
            }
#pragma unroll
            for (int mi = 0; mi < 2; mi++)
#pragma unroll
                for (int ni = 0; ni < 2; ni++)
                    acc[mi][ni] = __builtin_amdgcn_mfma_f32_16x16x32_bf16(
                        af[mi], bfr[ni], acc[mi][ni], 0, 0, 0);
        }
        __syncthreads();
        buf ^= 1;
    }

#pragma unroll
    for (int mi = 0; mi < 2; mi++) {
#pragma unroll
        for (int ni = 0; ni < 2; ni++) {
            const int col = j0 + wn + ni * 16 + l16;
            const float bval = bias[col];
#pragma unroll
            for (int r = 0; r < 4; r++) {
                const int row_o = i0 + wm + mi * 16 + quad * 4 + r;  // C/D: row=quad*4+reg
                float v = acc[mi][ni][r] + bval;
                if (RELU) v = fmaxf(v, 0.0f);
                if (MODE == 0) Cb[(size_t)row_o * N + col] = f2b(v);
                else if (MODE == 1) Cb[(size_t)col * ldt + row_o] = f2b(v);
                else Cf[(size_t)row_o * N + col] = v;
            }
        }
    }
}

// ---------------- flash attention: GEMM-style single-barrier pipelined K-loop ----------
// block = (64 q rows, head, split); t-tile = 32, K AND V double-buffered in LDS.
// Per iter: issue DMA for tile i+1 into buf^1, compute tile i from buf, one barrier
// (drains DMA + fences reads). Round 8 proved fragments must come from LDS
// (direct-global K = 200cyc L2 latency per read, serialized at low VGPR count).
// LDS 37 KB; (256,3) = 170-reg budget, ~110 live -> no spill.
__global__ __launch_bounds__(256, 3) void flash_attn(
    const unsigned short* __restrict__ Qg, const unsigned short* __restrict__ Kg,
    const unsigned short* __restrict__ Vt, unsigned short* __restrict__ Op,
    float* __restrict__ Lp)
{
    __shared__ __align__(16) unsigned short sK[2][32 * 128];  // [t][d], chunk swz key row&15
    __shared__ __align__(16) unsigned short sV[2][128 * 32];  // [d][t], chunk swz key row&3
    __shared__ __align__(16) unsigned short sP[4 * 16 * 40];  // wave-private P, padded

    const int tid = threadIdx.x;
    const int wave = tid >> 6, lane = tid & 63;
    const int quad = lane >> 4, l16 = lane & 15;
    const int head = blockIdx.y;
    const int q0 = blockIdx.x * 64;
    const int split = blockIdx.z;
    const int h0 = head * D_HEAD;

    // Q fragments direct from global (loop-invariant)
    bf16x8 aq[4];
    const int qrow = q0 + wave * 16 + l16;
#pragma unroll
    for (int ks = 0; ks < 4; ks++)
        aq[ks] = *(const bf16x8*)(Qg + (size_t)qrow * H_DIM + h0 + ks * 32 + quad * 8);

    unsigned short* myP = sP + wave * (16 * 40);

    // K staging: rows it*16 + wave*4 + (lane>>4); 16 chunks/row; 2 dma16/wave
    const int k_r = wave * 4 + (lane >> 4);
    const int k_c = (lane & 15) ^ (k_r & 15);
    // V staging: rows it*64 + wave*16 + (lane>>2); 4 chunks/row; 2 dma16/wave
    const int v_r = wave * 16 + (lane >> 2);
    const int v_c = (lane & 3) ^ (v_r & 3);

    const unsigned short* Kbase = Kg + h0;
    const unsigned short* Vbase = Vt + (size_t)h0 * S_LEN;
    const int kt0 = split * KV_PER;

    floatx4 z4 = {0.f, 0.f, 0.f, 0.f};
    floatx4 o[8];
#pragma unroll
    for (int i = 0; i < 8; i++) o[i] = z4;
    float l_r[4] = {0.f, 0.f, 0.f, 0.f};

    // prologue: stage tile 0 into buf 0
#pragma unroll
    for (int it = 0; it < 2; it++) {
        dma16(sK[0] + (it * 16 + wave * 4) * 128,
              Kbase + (size_t)(kt0 + k_r + it * 16) * H_DIM + k_c * 8);
        dma16(sV[0] + (it * 64 + wave * 16) * 32,
              Vbase + (size_t)(v_r + it * 64) * S_LEN + kt0 + v_c * 8);
    }
    __syncthreads();

    int buf = 0;
    for (int it0 = 0; it0 < KV_PER; it0 += 32) {
        // issue DMA for tile i+1 into the other buffer; overlapped with this
        // tile's compute, drained by the single loop-end barrier
        if (it0 + 32 < KV_PER) {
            const int nt = kt0 + it0 + 32;
#pragma unroll
            for (int it = 0; it < 2; it++) {
                dma16(sK[buf ^ 1] + (it * 16 + wave * 4) * 128,
                      Kbase + (size_t)(nt + k_r + it * 16) * H_DIM + k_c * 8);
                dma16(sV[buf ^ 1] + (it * 64 + wave * 16) * 32,
                      Vbase + (size_t)(v_r + it * 64) * S_LEN + nt + v_c * 8);
            }
        }

        // scores S[16 q][32 t] = Q K^T
        floatx4 sc[2];
#pragma unroll
        for (int ni = 0; ni < 2; ni++) {
            sc[ni] = z4;
#pragma unroll
            for (int ks = 0; ks < 4; ks++) {
                int p = (ks * 4 + quad) ^ l16;  // chunk swizzle, key row&15 = l16
                bf16x8 bk = *(const bf16x8*)(sK[buf] + (ni * 16 + l16) * 128 + p * 8);
                sc[ni] = __builtin_amdgcn_mfma_f32_16x16x32_bf16(aq[ks], bk, sc[ni], 0, 0, 0);
            }
        }

        // exp without max subtraction (scores provably small); per-lane l partial
#pragma unroll
        for (int ni = 0; ni < 2; ni++)
#pragma unroll
            for (int r = 0; r < 4; r++) {
                float p = __expf(sc[ni][r] * 0.03125f);  // 1/sqrt(H)=1/32
                sc[ni][r] = p;
                l_r[r] += p;
            }

        // P: C-layout -> wave-private padded LDS -> A-layout (no barrier)
#pragma unroll
        for (int ni = 0; ni < 2; ni++)
#pragma unroll
            for (int r = 0; r < 4; r++) {
                int prow = quad * 4 + r;
                myP[prow * 40 + ((ni * 16 + l16) ^ ((prow & 8) << 1))] = f2b(sc[ni][r]);
            }
        bf16x8 ap = *(const bf16x8*)(myP + l16 * 40 + ((quad * 8) ^ ((l16 & 8) << 1)));

        // PV from current V buffer (k = 32 -> single A-frag)
#pragma unroll
        for (int ni = 0; ni < 8; ni++) {
            int p = quad ^ (l16 & 3);  // chunk swizzle, key row&3
            bf16x8 bv = *(const bf16x8*)(sV[buf] + (ni * 16 + l16) * 32 + p * 8);
            o[ni] = __builtin_amdgcn_mfma_f32_16x16x32_bf16(ap, bv, o[ni], 0, 0, 0);
        }

        __syncthreads();  // drains next-tile DMA + fences reads of buf
        buf ^= 1;
    }

    // one-time l reduction across the 16-lane groups
#pragma unroll
    for (int r = 0; r < 4; r++)
#pragma unroll
        for (int off = 1; off < 16; off <<= 1)
            l_r[r] += __shfl_xor(l_r[r], off, 64);

#pragma unroll
    for (int r = 0; r < 4; r++) {
        float inv = 1.0f / l_r[r];
        int row = q0 + wave * 16 + quad * 4 + r;
#pragma unroll
        for (int ni = 0; ni < 8; ni++)
            Op[((size_t)split * S_LEN + row) * H_DIM + h0 + ni * 16 + l16] =
                f2b(o[ni][r] * inv);
        if (l16 == 0)
            Lp[(split * NHEAD + head) * S_LEN + row] = l_r[r];
    }
}

// ---------------- merge KV-split partials + residual add + LayerNorm ----------------
__global__ __launch_bounds__(256) void merge_add_layernorm(
    const float* __restrict__ t, const unsigned short* __restrict__ Op,
    const float* __restrict__ Lp,
    float* __restrict__ of, unsigned short* __restrict__ ob)
{
    __shared__ float red[8];
    const int row = blockIdx.x, tid = threadIdx.x;
    const int head = tid >> 5;  // 32 threads per head (128 dims / 4)
    const size_t base = (size_t)row * H_DIM + tid * 4;

    float l_s[KSPLIT];
    ushort4 os[KSPLIT];
#pragma unroll
    for (int sp = 0; sp < KSPLIT; sp++) {
        os[sp] = *(const ushort4*)(Op + ((size_t)sp * S_LEN + row) * H_DIM + tid * 4);
        l_s[sp] = Lp[(sp * NHEAD + head) * S_LEN + row];
    }
    float W = 0.f, a0 = 0.f, a1 = 0.f, a2 = 0.f, a3 = 0.f;
#pragma unroll
    for (int sp = 0; sp < KSPLIT; sp++) {
        float w = l_s[sp];  // no-max softmax: weight is the raw partial sum
        W += w;
        a0 += w * b2f(os[sp].x);
        a1 += w * b2f(os[sp].y);
        a2 += w * b2f(os[sp].z);
        a3 += w * b2f(os[sp].w);
    }
    float inv = 1.0f / W;
    float4 x = *(const float4*)(t + base);
    float v0 = x.x + a0 * inv, v1 = x.y + a1 * inv;
    float v2 = x.z + a2 * inv, v3 = x.w + a3 * inv;

    float s = v0 + v1 + v2 + v3;
    float q = v0 * v0 + v1 * v1 + v2 * v2 + v3 * v3;
#pragma unroll
    for (int off = 32; off >= 1; off >>= 1) {
        s += __shfl_xor(s, off, 64);
        q += __shfl_xor(q, off, 64);
    }
    if ((tid & 63) == 0) { red[tid >> 6] = s; red[4 + (tid >> 6)] = q; }
    __syncthreads();
    s = red[0] + red[1] + red[2] + red[3];
    q = red[4] + red[5] + red[6] + red[7];
    const float mean = s * (1.0f / (float)H_DIM);
    const float var = q * (1.0f / (float)H_DIM) - mean * mean;
    const float rstd = rsqrtf(var + 1e-5f);
    float o0 = (v0 - mean) * rstd, o1 = (v1 - mean) * rstd;
    float o2 = (v2 - mean) * rstd, o3 = (v3 - mean) * rstd;
    *(float4*)(of + base) = make_float4(o0, o1, o2, o3);
    *(ushort4*)(ob + base) = make_ushort4(f2b(o0), f2b(o1), f2b(o2), f2b(o3));
}

// ---------------- fused residual add + LayerNorm (fp32 in -> fp32 + bf16 out) ----------------
__global__ __launch_bounds__(256) void add_layernorm(
    const float* __restrict__ a, const float* __restrict__ b,
    float* __restrict__ of, unsigned short* __restrict__ ob)
{
    __shared__ float red[8];
    const int row = blockIdx.x, tid = threadIdx.x;
    const size_t base = (size_t)row * H_DIM + tid * 4;
    float4 x = *(const float4*)(a + base);
    float4 y = *(const float4*)(b + base);
    float v0 = x.x + y.x, v1 = x.y + y.y, v2 = x.z + y.z, v3 = x.w + y.w;
    float s = v0 + v1 + v2 + v3;
    float q = v0 * v0 + v1 * v1 + v2 * v2 + v3 * v3;
#pragma unroll
    for (int off = 32; off >= 1; off >>= 1) {
        s += __shfl_xor(s, off, 64);
        q += __shfl_xor(q, off, 64);
    }
    if ((tid & 63) == 0) { red[tid >> 6] = s; red[4 + (tid >> 6)] = q; }
    __syncthreads();
    s = red[0] + red[1] + red[2] + red[3];
    q = red[4] + red[5] + red[6] + red[7];
    const float mean = s * (1.0f / (float)H_DIM);
    const float var = q * (1.0f / (float)H_DIM) - mean * mean;
    const float rstd = rsqrtf(var + 1e-5f);
    float o0 = (v0 - mean) * rstd, o1 = (v1 - mean) * rstd;
    float o2 = (v2 - mean) * rstd, o3 = (v3 - mean) * rstd;
    *(float4*)(of + base) = make_float4(o0, o1, o2, o3);
    *(ushort4*)(ob + base) = make_ushort4(f2b(o0), f2b(o1), f2b(o2), f2b(o3));
}

extern "C" void kernel_launch(void* const* d_in, const int* in_sizes, int n_in,
                              void* d_out, int out_size, void* d_ws, size_t ws_size,
                              hipStream_t stream)
{
    (void)in_sizes; (void)n_in; (void)out_size; (void)ws_size;
    const float* in = (const float*)d_in[0];
    const float* Wq = (const float*)d_in[1];
    const float* bq = (const float*)d_in[2];
    const float* Wk = (const float*)d_in[3];
    const float* bk = (const float*)d_in[4];
    const float* Wv = (const float*)d_in[5];
    const float* bv = (const float*)d_in[6];
    const float* W1 = (const float*)d_in[7];
    const float* b1 = (const float*)d_in[8];
    const float* W2 = (const float*)d_in[9];
    const float* b2 = (const float*)d_in[10];

    char* ws = (char*)d_ws;
    const size_t MB = 1024 * 1024;
    float* t_f32 = (float*)(ws + 0 * MB);                    // 8 MB
    float* cf_f32 = (float*)(ws + 8 * MB);                   // 8 MB (ff2)
    unsigned short* t_b = (unsigned short*)(ws + 16 * MB);   // 4 MB
    unsigned short* K_b = (unsigned short*)(ws + 20 * MB);   // 4 MB
    unsigned short* Vt_b = (unsigned short*)(ws + 24 * MB);  // 4 MB, [NH,D,S]
    unsigned short* Q_b = (unsigned short*)(ws + 28 * MB);   // 4 MB (also ff1)
    unsigned short* WqT = (unsigned short*)(ws + 32 * MB);   // 2 MB each, [N,K]
    unsigned short* WkT = (unsigned short*)(ws + 34 * MB);
    unsigned short* WvT = (unsigned short*)(ws + 36 * MB);
    unsigned short* W1T = (unsigned short*)(ws + 38 * MB);
    unsigned short* W2T = (unsigned short*)(ws + 40 * MB);
    unsigned short* Op = (unsigned short*)(ws + 42 * MB);    // 16 MB [split][S][H] bf16
    float* Lp = (float*)(ws + 58 * MB);                      // 256 KB [split][NH][S]

    dim3 tb(32, 8);
    transpose_f2b<<<dim3(4, 32, 8), tb, 0, stream>>>(Wq, WqT, H_DIM, D_HEAD);
    transpose_f2b<<<dim3(4, 32, 8), tb, 0, stream>>>(Wk, WkT, H_DIM, D_HEAD);
    transpose_f2b<<<dim3(4, 32, 8), tb, 0, stream>>>(Wv, WvT, H_DIM, D_HEAD);
    transpose_f2b<<<dim3(32, 32, 1), tb, 0, stream>>>(W1, W1T, H_DIM, H_DIM);
    transpose_f2b<<<dim3(32, 32, 1), tb, 0, stream>>>(W2, W2T, H_DIM, H_DIM);

    posenc_kernel<<<(S_LEN * H_DIM) / 256, 256, 0, stream>>>(in, t_f32, t_b);

    dim3 gg(H_DIM / 64, S_LEN / 64);  // 16 x 32 = 512 blocks
    gemm_bt<0, false><<<gg, 256, 0, stream>>>(t_b, WkT, bk, nullptr, K_b, S_LEN, H_DIM, H_DIM, 0);
    gemm_bt<1, false><<<gg, 256, 0, stream>>>(t_b, WvT, bv, nullptr, Vt_b, S_LEN, H_DIM, H_DIM, S_LEN);

    for (int layer = 0; layer < 6; layer++) {
        gemm_bt<0, false><<<gg, 256, 0, stream>>>(t_b, WqT, bq, nullptr, Q_b, S_LEN, H_DIM, H_DIM, 0);
        flash_attn<<<dim3(S_LEN / 64, NHEAD, KSPLIT), 256, 0, stream>>>(Q_b, K_b, Vt_b, Op, Lp);
        merge_add_layernorm<<<S_LEN, 256, 0, stream>>>(t_f32, Op, Lp, t_f32, t_b);
        gemm_bt<0, true><<<gg, 256, 0, stream>>>(t_b, W1T, b1, nullptr, Q_b, S_LEN, H_DIM, H_DIM, 0);
        gemm_bt<2, false><<<gg, 256, 0, stream>>>(Q_b, W2T, b2, cf_f32, nullptr, S_LEN, H_DIM, H_DIM, 0);
        float* of = (layer == 5) ? (float*)d_out : t_f32;
        add_layernorm<<<S_LEN, 256, 0, stream>>>(t_f32, cf_f32, of, t_b);
    }
}

// Round 10
// 598.046 us; speedup vs baseline: 1.6331x; 1.0694x over previous
//
#include <hip/hip_runtime.h>

#define S_LEN 2048
#define H_DIM 1024
#define NHEAD 8
#define D_HEAD 128
#define KSPLIT 4
#define KV_PER (S_LEN / KSPLIT)  // 512 kv positions per split

typedef __bf16 bf16x8 __attribute__((ext_vector_type(8)));
typedef float floatx4 __attribute__((ext_vector_type(4)));

__device__ __forceinline__ float b2f(unsigned short u) {
    union { unsigned int i; float f; } v;
    v.i = ((unsigned int)u) << 16;
    return v.f;
}
__device__ __forceinline__ unsigned short f2b(float f) {
    union { float f; unsigned int i; } v;
    v.f = f;
    return (unsigned short)((v.i + 0x7fffu + ((v.i >> 16) & 1u)) >> 16);
}

// async global->LDS DMA, 16 B per lane; lds dst = wave-uniform base + lane*16
__device__ __forceinline__ void dma16(void* lds, const void* g) {
    __builtin_amdgcn_global_load_lds(
        (const __attribute__((address_space(1))) void*)g,
        (__attribute__((address_space(3))) void*)lds, 16, 0, 0);
}

// ---------------- positional encoding + input add (fp32 in -> fp32 + bf16 out) ----------------
__global__ __launch_bounds__(256) void posenc_kernel(
    const float* __restrict__ in, float* __restrict__ xf,
    unsigned short* __restrict__ xb)
{
    int g = blockIdx.x * 256 + threadIdx.x;
    int s = g >> 10;
    int h = g & 1023;
    float dv = powf(10000.0f, -(float)h * (1.0f / 512.0f));
    float ang = (float)s * dv;
    float pe = (h & 1) ? cosf(ang) : sinf(ang);
    float x = in[g] + pe;
    xf[g] = x;
    xb[g] = f2b(x);
}

// ---------------- all 5 weight transposes in ONE dispatch (fp32 -> bf16) ------------
// z<8: Wq head z; z<16: Wk; z<24: Wv; z<32: W1 col-chunk; z<40: W2 col-chunk.
// Each z transposes a 1024(R) x 128(C) panel; output row-stride is always 1024.
__global__ __launch_bounds__(256) void transpose_all(
    const float* __restrict__ Wq, const float* __restrict__ Wk,
    const float* __restrict__ Wv, const float* __restrict__ W1,
    const float* __restrict__ W2,
    unsigned short* __restrict__ WqT, unsigned short* __restrict__ WkT,
    unsigned short* __restrict__ WvT, unsigned short* __restrict__ W1T,
    unsigned short* __restrict__ W2T)
{
    __shared__ unsigned short tile[32][33];
    const int z = blockIdx.z;
    const float* ih;
    unsigned short* oh;
    int ldin;
    if (z < 8)       { ih = Wq + (size_t)z * 131072;        oh = WqT + (size_t)z * 131072;        ldin = 128; }
    else if (z < 16) { ih = Wk + (size_t)(z - 8) * 131072;  oh = WkT + (size_t)(z - 8) * 131072;  ldin = 128; }
    else if (z < 24) { ih = Wv + (size_t)(z - 16) * 131072; oh = WvT + (size_t)(z - 16) * 131072; ldin = 128; }
    else if (z < 32) { ih = W1 + (size_t)(z - 24) * 128;    oh = W1T + (size_t)(z - 24) * 131072; ldin = 1024; }
    else             { ih = W2 + (size_t)(z - 32) * 128;    oh = W2T + (size_t)(z - 32) * 131072; ldin = 1024; }
    const int r0 = blockIdx.y * 32, c0 = blockIdx.x * 32;
    const int tx = threadIdx.x, ty = threadIdx.y;
    for (int i = ty; i < 32; i += 8)
        tile[i][tx] = f2b(ih[(size_t)(r0 + i) * ldin + c0 + tx]);
    __syncthreads();
    for (int i = ty; i < 32; i += 8)
        oh[(size_t)(c0 + i) * 1024 + r0 + tx] = tile[tx][i];
}

// ---------------- GEMM core: 64x64 tile, BK=64, DMA dbuf, XOR-swizzled LDS ------------
// MODE 0: bf16 out [M,N]; MODE 1: bf16 out transposed [N, ldt]; MODE 2: f32 out [M,N]
template <int MODE, bool RELU>
__device__ __forceinline__ void gemm_core(
    unsigned short* sA0, unsigned short* sB0,  // each 2*64*64 shorts
    const unsigned short* A, const unsigned short* Bt,
    const float* bias, float* Cf, unsigned short* Cb,
    int N, int K, int ldt, int i0, int j0)
{
    const int tid = threadIdx.x;
    const int wave = tid >> 6, lane = tid & 63;
    const int quad = lane >> 4, l16 = lane & 15;
    const int wm = (wave >> 1) * 32, wn = (wave & 1) * 32;

    const int srow = lane >> 3;
    const int schunk = (lane & 7) ^ (srow & 7);
    const unsigned short* Ap0 = A + (size_t)(i0 + wave * 8 + srow) * K + schunk * 8;
    const unsigned short* Ap1 = A + (size_t)(i0 + 32 + wave * 8 + srow) * K + schunk * 8;
    const unsigned short* Bp0 = Bt + (size_t)(j0 + wave * 8 + srow) * K + schunk * 8;
    const unsigned short* Bp1 = Bt + (size_t)(j0 + 32 + wave * 8 + srow) * K + schunk * 8;
    const int ld0 = (wave * 8) * 64, ld1 = (32 + wave * 8) * 64;

    floatx4 z4 = {0.f, 0.f, 0.f, 0.f};
    floatx4 acc[2][2];
#pragma unroll
    for (int i = 0; i < 2; i++)
#pragma unroll
        for (int j = 0; j < 2; j++) acc[i][j] = z4;

    dma16(sA0 + ld0, Ap0);
    dma16(sA0 + ld1, Ap1);
    dma16(sB0 + ld0, Bp0);
    dma16(sB0 + ld1, Bp1);
    __syncthreads();

    int buf = 0;
    for (int k0 = 0; k0 < K; k0 += 64) {
        if (k0 + 64 < K) {
            unsigned short* nA = sA0 + (buf ^ 1) * 4096;
            unsigned short* nB = sB0 + (buf ^ 1) * 4096;
            dma16(nA + ld0, Ap0 + k0 + 64);
            dma16(nA + ld1, Ap1 + k0 + 64);
            dma16(nB + ld0, Bp0 + k0 + 64);
            dma16(nB + ld1, Bp1 + k0 + 64);
        }
        const unsigned short* cA = sA0 + buf * 4096;
        const unsigned short* cB = sB0 + buf * 4096;
#pragma unroll
        for (int kh = 0; kh < 2; kh++) {
            bf16x8 af[2], bfr[2];
#pragma unroll
            for (int mi = 0; mi < 2; mi++) {
                int row = wm + mi * 16 + l16;
                int p = (kh * 4 + quad) ^ (l16 & 7);
                af[mi] = *(const bf16x8*)(cA + row * 64 + p * 8);
            }
#pragma unroll
            for (int ni = 0; ni < 2; ni++) {
                int row = wn + ni * 16 + l16;
                int p = (kh * 4 + quad) ^ (l16 & 7);
                bfr[ni] = *(const bf16x8*)(cB + row * 64 + p * 8);
            }
#pragma unroll
            for (int mi = 0; mi < 2; mi++)
#pragma unroll
                for (int ni = 0; ni < 2; ni++)
                    acc[mi][ni] = __builtin_amdgcn_mfma_f32_16x16x32_bf16(
                        af[mi], bfr[ni], acc[mi][ni], 0, 0, 0);
        }
        __syncthreads();
        buf ^= 1;
    }

#pragma unroll
    for (int mi = 0; mi < 2; mi++) {
#pragma unroll
        for (int ni = 0; ni < 2; ni++) {
            const int col = j0 + wn + ni * 16 + l16;
            const float bval = bias[col];
#pragma unroll
            for (int r = 0; r < 4; r++) {
                const int row_o = i0 + wm + mi * 16 + quad * 4 + r;  // C/D: row=quad*4+reg
                float v = acc[mi][ni][r] + bval;
                if (RELU) v = fmaxf(v, 0.0f);
                if (MODE == 0) Cb[(size_t)row_o * N + col] = f2b(v);
                else if (MODE == 1) Cb[(size_t)col * ldt + row_o] = f2b(v);
                else Cf[(size_t)row_o * N + col] = v;
            }
        }
    }
}

template <int MODE, bool RELU>
__global__ __launch_bounds__(256, 4) void gemm_bt(
    const unsigned short* __restrict__ A, const unsigned short* __restrict__ Bt,
    const float* __restrict__ bias, float* __restrict__ Cf,
    unsigned short* __restrict__ Cb, int M, int N, int K, int ldt)
{
    __shared__ __align__(16) unsigned short sA[2 * 64 * 64];
    __shared__ __align__(16) unsigned short sB[2 * 64 * 64];
    gemm_core<MODE, RELU>(sA, sB, A, Bt, bias, Cf, Cb, N, K, ldt,
                          blockIdx.y * 64, blockIdx.x * 64);
}

// K and V projection GEMMs fused into one dispatch (z=0 -> K, z=1 -> V^T)
__global__ __launch_bounds__(256, 4) void gemm_kv(
    const unsigned short* __restrict__ A,
    const unsigned short* __restrict__ WkT, const unsigned short* __restrict__ WvT,
    const float* __restrict__ bk, const float* __restrict__ bv,
    unsigned short* __restrict__ Kb, unsigned short* __restrict__ Vtb)
{
    __shared__ __align__(16) unsigned short sA[2 * 64 * 64];
    __shared__ __align__(16) unsigned short sB[2 * 64 * 64];
    if (blockIdx.z == 0)
        gemm_core<0, false>(sA, sB, A, WkT, bk, nullptr, Kb, H_DIM, H_DIM, 0,
                            blockIdx.y * 64, blockIdx.x * 64);
    else
        gemm_core<1, false>(sA, sB, A, WvT, bv, nullptr, Vtb, H_DIM, H_DIM, S_LEN,
                            blockIdx.y * 64, blockIdx.x * 64);
}

// ---------------- flash attention: single-barrier pipeline, t-tile 64, dynamic LDS ----
// block = (64 q rows, head, split). K AND V double-buffered (73 KB LDS via dynamic
// shared memory opt-in, 2 blocks/CU): DMA for tile i+1 issued at top of tile i,
// drained by the single loop-end barrier -> fully overlapped with QK+exp+P+PV.
// r8 proved fragments must come from LDS; r9 proved t=32 doubles fixed costs.
__global__ __launch_bounds__(256, 2) void flash_attn(
    const unsigned short* __restrict__ Qg, const unsigned short* __restrict__ Kg,
    const unsigned short* __restrict__ Vt, unsigned short* __restrict__ Op,
    float* __restrict__ Lp)
{
    extern __shared__ __align__(16) unsigned short smem[];
    unsigned short* sK0 = smem;               // 2 x 64x128
    unsigned short* sV0 = smem + 16384;       // 2 x 128x64
    unsigned short* sP = smem + 32768;        // 4 x 16x72 (wave-private)

    const int tid = threadIdx.x;
    const int wave = tid >> 6, lane = tid & 63;
    const int quad = lane >> 4, l16 = lane & 15;
    const int head = blockIdx.y;
    const int q0 = blockIdx.x * 64;
    const int split = blockIdx.z;
    const int h0 = head * D_HEAD;

    // Q fragments direct from global (loop-invariant)
    bf16x8 aq[4];
    const int qrow = q0 + wave * 16 + l16;
#pragma unroll
    for (int ks = 0; ks < 4; ks++)
        aq[ks] = *(const bf16x8*)(Qg + (size_t)qrow * H_DIM + h0 + ks * 32 + quad * 8);

    unsigned short* myP = sP + wave * (16 * 72);

    // K staging: 16 lanes/row, rows it*16 + wave*4 + (lane>>4); chunk key row&15
    const int k_r = wave * 4 + (lane >> 4);
    const int k_c = (lane & 15) ^ (k_r & 15);
    // V staging: 8 lanes/row, rows it*32 + wave*8 + (lane>>3); chunk key row&7
    const int v_r = wave * 8 + (lane >> 3);
    const int v_c = (lane & 7) ^ (v_r & 7);

    const unsigned short* Kbase = Kg + h0;
    const unsigned short* Vbase = Vt + (size_t)h0 * S_LEN;
    const int kt0 = split * KV_PER;

    floatx4 z4 = {0.f, 0.f, 0.f, 0.f};
    floatx4 o[8];
#pragma unroll
    for (int i = 0; i < 8; i++) o[i] = z4;
    float l_r[4] = {0.f, 0.f, 0.f, 0.f};

    // prologue: stage tile 0 into buf 0
#pragma unroll
    for (int it = 0; it < 4; it++) {
        dma16(sK0 + (wave * 4 + it * 16) * 128,
              Kbase + (size_t)(kt0 + k_r + it * 16) * H_DIM + k_c * 8);
        dma16(sV0 + (wave * 8 + it * 32) * 64,
              Vbase + (size_t)(v_r + it * 32) * S_LEN + kt0 + v_c * 8);
    }
    __syncthreads();

    int buf = 0;
    for (int it0 = 0; it0 < KV_PER; it0 += 64) {
        const int t0 = kt0 + it0;
        // issue DMA for tile i+1 into the other buffer; drained by the single
        // loop-end barrier, fully overlapped with this tile's compute
        if (it0 + 64 < KV_PER) {
            const int nt = t0 + 64;
            unsigned short* nK = sK0 + (buf ^ 1) * 8192;
            unsigned short* nV = sV0 + (buf ^ 1) * 8192;
#pragma unroll
            for (int it = 0; it < 4; it++) {
                dma16(nK + (wave * 4 + it * 16) * 128,
                      Kbase + (size_t)(nt + k_r + it * 16) * H_DIM + k_c * 8);
                dma16(nV + (wave * 8 + it * 32) * 64,
                      Vbase + (size_t)(v_r + it * 32) * S_LEN + nt + v_c * 8);
            }
        }
        const unsigned short* cK = sK0 + buf * 8192;
        const unsigned short* cV = sV0 + buf * 8192;

        // scores S[16 q][64 t] = Q K^T
        floatx4 sc[4];
#pragma unroll
        for (int ni = 0; ni < 4; ni++) {
            sc[ni] = z4;
#pragma unroll
            for (int ks = 0; ks < 4; ks++) {
                int p = (ks * 4 + quad) ^ l16;  // chunk swizzle, key row&15 = l16
                bf16x8 bk = *(const bf16x8*)(cK + (ni * 16 + l16) * 128 + p * 8);
                sc[ni] = __builtin_amdgcn_mfma_f32_16x16x32_bf16(aq[ks], bk, sc[ni], 0, 0, 0);
            }
        }

        // exp without max subtraction (scores provably small); per-lane l partial
#pragma unroll
        for (int ni = 0; ni < 4; ni++)
#pragma unroll
            for (int r = 0; r < 4; r++) {
                float p = __expf(sc[ni][r] * 0.03125f);  // 1/sqrt(H)=1/32
                sc[ni][r] = p;
                l_r[r] += p;
            }

        // P: C-layout -> wave-private padded LDS -> A-layout (no barrier)
#pragma unroll
        for (int ni = 0; ni < 4; ni++)
#pragma unroll
            for (int r = 0; r < 4; r++) {
                int prow = quad * 4 + r;
                myP[prow * 72 + ((ni * 16 + l16) ^ ((prow & 8) << 1))] = f2b(sc[ni][r]);
            }
        bf16x8 ap[2];
#pragma unroll
        for (int ks = 0; ks < 2; ks++)
            ap[ks] = *(const bf16x8*)(myP + l16 * 72 + ((ks * 32 + quad * 8) ^ ((l16 & 8) << 1)));

        // PV from current V buffer
#pragma unroll
        for (int ni = 0; ni < 8; ni++) {
#pragma unroll
            for (int ks = 0; ks < 2; ks++) {
                int p = (ks * 4 + quad) ^ (l16 & 7);  // key row&7
                bf16x8 bv = *(const bf16x8*)(cV + (ni * 16 + l16) * 64 + p * 8);
                o[ni] = __builtin_amdgcn_mfma_f32_16x16x32_bf16(ap[ks], bv, o[ni], 0, 0, 0);
            }
        }

        __syncthreads();  // drains next-tile DMA + fences reads of buf
        buf ^= 1;
    }

    // one-time l reduction across the 16-lane groups
#pragma unroll
    for (int r = 0; r < 4; r++)
#pragma unroll
        for (int off = 1; off < 16; off <<= 1)
            l_r[r] += __shfl_xor(l_r[r], off, 64);

#pragma unroll
    for (int r = 0; r < 4; r++) {
        float inv = 1.0f / l_r[r];
        int row = q0 + wave * 16 + quad * 4 + r;
#pragma unroll
        for (int ni = 0; ni < 8; ni++)
            Op[((size_t)split * S_LEN + row) * H_DIM + h0 + ni * 16 + l16] =
                f2b(o[ni][r] * inv);
        if (l16 == 0)
            Lp[(split * NHEAD + head) * S_LEN + row] = l_r[r];
    }
}

// ---------------- merge KV-split partials + residual add + LayerNorm ----------------
__global__ __launch_bounds__(256) void merge_add_layernorm(
    const float* __restrict__ t, const unsigned short* __restrict__ Op,
    const float* __restrict__ Lp,
    float* __restrict__ of, unsigned short* __restrict__ ob)
{
    __shared__ float red[8];
    const int row = blockIdx.x, tid = threadIdx.x;
    const int head = tid >> 5;  // 32 threads per head (128 dims / 4)
    const size_t base = (size_t)row * H_DIM + tid * 4;

    float l_s[KSPLIT];
    ushort4 os[KSPLIT];
#pragma unroll
    for (int sp = 0; sp < KSPLIT; sp++) {
        os[sp] = *(const ushort4*)(Op + ((size_t)sp * S_LEN + row) * H_DIM + tid * 4);
        l_s[sp] = Lp[(sp * NHEAD + head) * S_LEN + row];
    }
    float W = 0.f, a0 = 0.f, a1 = 0.f, a2 = 0.f, a3 = 0.f;
#pragma unroll
    for (int sp = 0; sp < KSPLIT; sp++) {
        float w = l_s[sp];  // no-max softmax: weight is the raw partial sum
        W += w;
        a0 += w * b2f(os[sp].x);
        a1 += w * b2f(os[sp].y);
        a2 += w * b2f(os[sp].z);
        a3 += w * b2f(os[sp].w);
    }
    float inv = 1.0f / W;
    float4 x = *(const float4*)(t + base);
    float v0 = x.x + a0 * inv, v1 = x.y + a1 * inv;
    float v2 = x.z + a2 * inv, v3 = x.w + a3 * inv;

    float s = v0 + v1 + v2 + v3;
    float q = v0 * v0 + v1 * v1 + v2 * v2 + v3 * v3;
#pragma unroll
    for (int off = 32; off >= 1; off >>= 1) {
        s += __shfl_xor(s, off, 64);
        q += __shfl_xor(q, off, 64);
    }
    if ((tid & 63) == 0) { red[tid >> 6] = s; red[4 + (tid >> 6)] = q; }
    __syncthreads();
    s = red[0] + red[1] + red[2] + red[3];
    q = red[4] + red[5] + red[6] + red[7];
    const float mean = s * (1.0f / (float)H_DIM);
    const float var = q * (1.0f / (float)H_DIM) - mean * mean;
    const float rstd = rsqrtf(var + 1e-5f);
    float o0 = (v0 - mean) * rstd, o1 = (v1 - mean) * rstd;
    float o2 = (v2 - mean) * rstd, o3 = (v3 - mean) * rstd;
    *(float4*)(of + base) = make_float4(o0, o1, o2, o3);
    *(ushort4*)(ob + base) = make_ushort4(f2b(o0), f2b(o1), f2b(o2), f2b(o3));
}

// ---------------- fused residual add + LayerNorm (fp32 in -> fp32 + bf16 out) ----------------
__global__ __launch_bounds__(256) void add_layernorm(
    const float* __restrict__ a, const float* __restrict__ b,
    float* __restrict__ of, unsigned short* __restrict__ ob)
{
    __shared__ float red[8];
    const int row = blockIdx.x, tid = threadIdx.x;
    const size_t base = (size_t)row * H_DIM + tid * 4;
    float4 x = *(const float4*)(a + base);
    float4 y = *(const float4*)(b + base);
    float v0 = x.x + y.x, v1 = x.y + y.y, v2 = x.z + y.z, v3 = x.w + y.w;
    float s = v0 + v1 + v2 + v3;
    float q = v0 * v0 + v1 * v1 + v2 * v2 + v3 * v3;
#pragma unroll
    for (int off = 32; off >= 1; off >>= 1) {
        s += __shfl_xor(s, off, 64);
        q += __shfl_xor(q, off, 64);
    }
    if ((tid & 63) == 0) { red[tid >> 6] = s; red[4 + (tid >> 6)] = q; }
    __syncthreads();
    s = red[0] + red[1] + red[2] + red[3];
    q = red[4] + red[5] + red[6] + red[7];
    const float mean = s * (1.0f / (float)H_DIM);
    const float var = q * (1.0f / (float)H_DIM) - mean * mean;
    const float rstd = rsqrtf(var + 1e-5f);
    float o0 = (v0 - mean) * rstd, o1 = (v1 - mean) * rstd;
    float o2 = (v2 - mean) * rstd, o3 = (v3 - mean) * rstd;
    *(float4*)(of + base) = make_float4(o0, o1, o2, o3);
    *(ushort4*)(ob + base) = make_ushort4(f2b(o0), f2b(o1), f2b(o2), f2b(o3));
}

extern "C" void kernel_launch(void* const* d_in, const int* in_sizes, int n_in,
                              void* d_out, int out_size, void* d_ws, size_t ws_size,
                              hipStream_t stream)
{
    (void)in_sizes; (void)n_in; (void)out_size; (void)ws_size;
    const float* in = (const float*)d_in[0];
    const float* Wq = (const float*)d_in[1];
    const float* bq = (const float*)d_in[2];
    const float* Wk = (const float*)d_in[3];
    const float* bk = (const float*)d_in[4];
    const float* Wv = (const float*)d_in[5];
    const float* bv = (const float*)d_in[6];
    const float* W1 = (const float*)d_in[7];
    const float* b1 = (const float*)d_in[8];
    const float* W2 = (const float*)d_in[9];
    const float* b2 = (const float*)d_in[10];

    char* ws = (char*)d_ws;
    const size_t MB = 1024 * 1024;
    float* t_f32 = (float*)(ws + 0 * MB);                    // 8 MB
    float* cf_f32 = (float*)(ws + 8 * MB);                   // 8 MB (ff2)
    unsigned short* t_b = (unsigned short*)(ws + 16 * MB);   // 4 MB
    unsigned short* K_b = (unsigned short*)(ws + 20 * MB);   // 4 MB
    unsigned short* Vt_b = (unsigned short*)(ws + 24 * MB);  // 4 MB, [NH,D,S]
    unsigned short* Q_b = (unsigned short*)(ws + 28 * MB);   // 4 MB (also ff1)
    unsigned short* WqT = (unsigned short*)(ws + 32 * MB);   // 2 MB each, [N,K]
    unsigned short* WkT = (unsigned short*)(ws + 34 * MB);
    unsigned short* WvT = (unsigned short*)(ws + 36 * MB);
    unsigned short* W1T = (unsigned short*)(ws + 38 * MB);
    unsigned short* W2T = (unsigned short*)(ws + 40 * MB);
    unsigned short* Op = (unsigned short*)(ws + 42 * MB);    // 16 MB [split][S][H] bf16
    float* Lp = (float*)(ws + 58 * MB);                      // 256 KB [split][NH][S]

    // opt in to >64 KB dynamic LDS for flash (73 KB; 2 blocks/CU of 160 KB)
    (void)hipFuncSetAttribute(reinterpret_cast<const void*>(&flash_attn),
                              hipFuncAttributeMaxDynamicSharedMemorySize, 74752);

    transpose_all<<<dim3(4, 32, 40), dim3(32, 8), 0, stream>>>(
        Wq, Wk, Wv, W1, W2, WqT, WkT, WvT, W1T, W2T);

    posenc_kernel<<<(S_LEN * H_DIM) / 256, 256, 0, stream>>>(in, t_f32, t_b);

    dim3 gg(H_DIM / 64, S_LEN / 64);  // 16 x 32 = 512 blocks
    gemm_kv<<<dim3(16, 32, 2), 256, 0, stream>>>(t_b, WkT, WvT, bk, bv, K_b, Vt_b);

    for (int layer = 0; layer < 6; layer++) {
        gemm_bt<0, false><<<gg, 256, 0, stream>>>(t_b, WqT, bq, nullptr, Q_b, S_LEN, H_DIM, H_DIM, 0);
        flash_attn<<<dim3(S_LEN / 64, NHEAD, KSPLIT), 256, 74752, stream>>>(Q_b, K_b, Vt_b, Op, Lp);
        merge_add_layernorm<<<S_LEN, 256, 0, stream>>>(t_f32, Op, Lp, t_f32, t_b);
        gemm_bt<0, true><<<gg, 256, 0, stream>>>(t_b, W1T, b1, nullptr, Q_b, S_LEN, H_DIM, H_DIM, 0);
        gemm_bt<2, false><<<gg, 256, 0, stream>>>(Q_b, W2T, b2, cf_f32, nullptr, S_LEN, H_DIM, H_DIM, 0);
        float* of = (layer == 5) ? (float*)d_out : t_f32;
        add_layernorm<<<S_LEN, 256, 0, stream>>>(t_f32, cf_f32, of, t_b);
    }
}

// Round 11
// 593.141 us; speedup vs baseline: 1.6466x; 1.0083x over previous
//
#include <hip/hip_runtime.h>

#define S_LEN 2048
#define H_DIM 1024
#define NHEAD 8
#define D_HEAD 128
#define KSPLIT 2
#define KV_PER (S_LEN / KSPLIT)  // 1024 kv positions per split

typedef __bf16 bf16x8 __attribute__((ext_vector_type(8)));
typedef float floatx4 __attribute__((ext_vector_type(4)));

__device__ __forceinline__ float b2f(unsigned short u) {
    union { unsigned int i; float f; } v;
    v.i = ((unsigned int)u) << 16;
    return v.f;
}
__device__ __forceinline__ unsigned short f2b(float f) {
    union { float f; unsigned int i; } v;
    v.f = f;
    return (unsigned short)((v.i + 0x7fffu + ((v.i >> 16) & 1u)) >> 16);
}

// async global->LDS DMA, 16 B per lane; lds dst = wave-uniform base + lane*16
__device__ __forceinline__ void dma16(void* lds, const void* g) {
    __builtin_amdgcn_global_load_lds(
        (const __attribute__((address_space(1))) void*)g,
        (__attribute__((address_space(3))) void*)lds, 16, 0, 0);
}

// ---------------- positional encoding + input add (fp32 in -> fp32 + bf16 out) ----------------
__global__ __launch_bounds__(256) void posenc_kernel(
    const float* __restrict__ in, float* __restrict__ xf,
    unsigned short* __restrict__ xb)
{
    int g = blockIdx.x * 256 + threadIdx.x;
    int s = g >> 10;
    int h = g & 1023;
    float dv = powf(10000.0f, -(float)h * (1.0f / 512.0f));
    float ang = (float)s * dv;
    float pe = (h & 1) ? cosf(ang) : sinf(ang);
    float x = in[g] + pe;
    xf[g] = x;
    xb[g] = f2b(x);
}

// ---------------- all 5 weight transposes in ONE dispatch (fp32 -> bf16) ------------
__global__ __launch_bounds__(256) void transpose_all(
    const float* __restrict__ Wq, const float* __restrict__ Wk,
    const float* __restrict__ Wv, const float* __restrict__ W1,
    const float* __restrict__ W2,
    unsigned short* __restrict__ WqT, unsigned short* __restrict__ WkT,
    unsigned short* __restrict__ WvT, unsigned short* __restrict__ W1T,
    unsigned short* __restrict__ W2T)
{
    __shared__ unsigned short tile[32][33];
    const int z = blockIdx.z;
    const float* ih;
    unsigned short* oh;
    int ldin;
    if (z < 8)       { ih = Wq + (size_t)z * 131072;        oh = WqT + (size_t)z * 131072;        ldin = 128; }
    else if (z < 16) { ih = Wk + (size_t)(z - 8) * 131072;  oh = WkT + (size_t)(z - 8) * 131072;  ldin = 128; }
    else if (z < 24) { ih = Wv + (size_t)(z - 16) * 131072; oh = WvT + (size_t)(z - 16) * 131072; ldin = 128; }
    else if (z < 32) { ih = W1 + (size_t)(z - 24) * 128;    oh = W1T + (size_t)(z - 24) * 131072; ldin = 1024; }
    else             { ih = W2 + (size_t)(z - 32) * 128;    oh = W2T + (size_t)(z - 32) * 131072; ldin = 1024; }
    const int r0 = blockIdx.y * 32, c0 = blockIdx.x * 32;
    const int tx = threadIdx.x, ty = threadIdx.y;
    for (int i = ty; i < 32; i += 8)
        tile[i][tx] = f2b(ih[(size_t)(r0 + i) * ldin + c0 + tx]);
    __syncthreads();
    for (int i = ty; i < 32; i += 8)
        oh[(size_t)(c0 + i) * 1024 + r0 + tx] = tile[tx][i];
}

// ---------------- GEMM 128x128 core: wave=64x64 (4x4), BK=64, DMA dbuf ----------------
// MFMA:ds_read ratio 2:1 (16 MFMAs per 8 b128 reads per kh-pair) — halves the LDS
// floor vs the old 64x64/wave32x32 (1:1) design. 64 KB dynamic LDS, hardcoded
// M=2048,N=1024,K=1024. MODE 0: bf16 [M,N]; 1: bf16 transposed [N,ldt]; 2: f32 [M,N].
template <int MODE, bool RELU>
__device__ __forceinline__ void gemm128_core(
    unsigned short* sA, unsigned short* sB,
    const unsigned short* A, const unsigned short* Bt,
    const float* bias, float* Cf, unsigned short* Cb, int ldt, int i0, int j0)
{
    const int K = H_DIM;
    const int tid = threadIdx.x;
    const int wave = tid >> 6, lane = tid & 63;
    const int quad = lane >> 4, l16 = lane & 15;
    const int wm = (wave >> 1) * 64, wn = (wave & 1) * 64;

    // staging: 8 chunks(16B)/row, 8 lanes/row, 8 rows/instr/wave, 4 instrs per matrix
    const int srow = lane >> 3;
    const int schunk = (lane & 7) ^ srow;  // XOR swizzle, key = row&7 (= srow)
    const unsigned short* Ap = A + (size_t)(i0 + wave * 8 + srow) * K + schunk * 8;
    const unsigned short* Bp = Bt + (size_t)(j0 + wave * 8 + srow) * K + schunk * 8;

    floatx4 z4 = {0.f, 0.f, 0.f, 0.f};
    floatx4 acc[4][4];
#pragma unroll
    for (int i = 0; i < 4; i++)
#pragma unroll
        for (int j = 0; j < 4; j++) acc[i][j] = z4;

    // prologue: stage slab 0 into buf 0
#pragma unroll
    for (int it = 0; it < 4; it++) {
        const int lb = (wave * 8 + it * 32) * 64;
        dma16(sA + lb, Ap + (size_t)(it * 32) * K);
        dma16(sB + lb, Bp + (size_t)(it * 32) * K);
    }
    __syncthreads();

    int buf = 0;
    for (int k0 = 0; k0 < K; k0 += 64) {
        if (k0 + 64 < K) {  // stage next slab into other buffer (drained by barrier)
            unsigned short* nA = sA + (buf ^ 1) * 8192;
            unsigned short* nB = sB + (buf ^ 1) * 8192;
#pragma unroll
            for (int it = 0; it < 4; it++) {
                const int lb = (wave * 8 + it * 32) * 64;
                dma16(nA + lb, Ap + (size_t)(it * 32) * K + k0 + 64);
                dma16(nB + lb, Bp + (size_t)(it * 32) * K + k0 + 64);
            }
        }
        const unsigned short* cA = sA + buf * 8192;
        const unsigned short* cB = sB + buf * 8192;
#pragma unroll
        for (int kh = 0; kh < 2; kh++) {
            bf16x8 af[4], bfr[4];
#pragma unroll
            for (int mi = 0; mi < 4; mi++) {
                int row = wm + mi * 16 + l16;
                int p = (kh * 4 + quad) ^ (l16 & 7);
                af[mi] = *(const bf16x8*)(cA + row * 64 + p * 8);
            }
#pragma unroll
            for (int ni = 0; ni < 4; ni++) {
                int row = wn + ni * 16 + l16;
                int p = (kh * 4 + quad) ^ (l16 & 7);
                bfr[ni] = *(const bf16x8*)(cB + row * 64 + p * 8);
            }
#pragma unroll
            for (int mi = 0; mi < 4; mi++)
#pragma unroll
                for (int ni = 0; ni < 4; ni++)
                    acc[mi][ni] = __builtin_amdgcn_mfma_f32_16x16x32_bf16(
                        af[mi], bfr[ni], acc[mi][ni], 0, 0, 0);
        }
        __syncthreads();
        buf ^= 1;
    }

#pragma unroll
    for (int mi = 0; mi < 4; mi++) {
#pragma unroll
        for (int ni = 0; ni < 4; ni++) {
            const int col = j0 + wn + ni * 16 + l16;
            const float bval = bias[col];
#pragma unroll
            for (int r = 0; r < 4; r++) {
                const int row_o = i0 + wm + mi * 16 + quad * 4 + r;  // C/D: row=quad*4+reg
                float v = acc[mi][ni][r] + bval;
                if (RELU) v = fmaxf(v, 0.0f);
                if (MODE == 0) Cb[(size_t)row_o * H_DIM + col] = f2b(v);
                else if (MODE == 1) Cb[(size_t)col * ldt + row_o] = f2b(v);
                else Cf[(size_t)row_o * H_DIM + col] = v;
            }
        }
    }
}

template <int MODE, bool RELU>
__global__ __launch_bounds__(256, 2) void gemm128(
    const unsigned short* __restrict__ A, const unsigned short* __restrict__ Bt,
    const float* __restrict__ bias, float* __restrict__ Cf,
    unsigned short* __restrict__ Cb, int ldt)
{
    extern __shared__ __align__(16) unsigned short gsm[];
    gemm128_core<MODE, RELU>(gsm, gsm + 16384, A, Bt, bias, Cf, Cb, ldt,
                             blockIdx.y * 128, blockIdx.x * 128);
}

// K and V projection GEMMs fused (z=0 -> K, z=1 -> V^T); 256 blocks = full chip
__global__ __launch_bounds__(256, 2) void gemm_kv(
    const unsigned short* __restrict__ A,
    const unsigned short* __restrict__ WkT, const unsigned short* __restrict__ WvT,
    const float* __restrict__ bk, const float* __restrict__ bv,
    unsigned short* __restrict__ Kb, unsigned short* __restrict__ Vtb)
{
    extern __shared__ __align__(16) unsigned short gsm[];
    if (blockIdx.z == 0)
        gemm128_core<0, false>(gsm, gsm + 16384, A, WkT, bk, nullptr, Kb, 0,
                               blockIdx.y * 128, blockIdx.x * 128);
    else
        gemm128_core<1, false>(gsm, gsm + 16384, A, WvT, bv, nullptr, Vtb, S_LEN,
                               blockIdx.y * 128, blockIdx.x * 128);
}

// ---------------- flash attention: single-barrier pipeline, t-tile 64, dynamic LDS ----
// block = (64 q rows, head, split). K AND V double-buffered (73 KB LDS, 2 blocks/CU):
// DMA for tile i+1 issued at top of tile i, drained by the single loop-end barrier.
// KSPLIT=2: 512 blocks = exactly 2/CU; halves Op traffic + merge cost.
__global__ __launch_bounds__(256, 2) void flash_attn(
    const unsigned short* __restrict__ Qg, const unsigned short* __restrict__ Kg,
    const unsigned short* __restrict__ Vt, unsigned short* __restrict__ Op,
    float* __restrict__ Lp)
{
    extern __shared__ __align__(16) unsigned short smem[];
    unsigned short* sK0 = smem;               // 2 x 64x128
    unsigned short* sV0 = smem + 16384;       // 2 x 128x64
    unsigned short* sP = smem + 32768;        // 4 x 16x72 (wave-private)

    const int tid = threadIdx.x;
    const int wave = tid >> 6, lane = tid & 63;
    const int quad = lane >> 4, l16 = lane & 15;
    const int head = blockIdx.y;
    const int q0 = blockIdx.x * 64;
    const int split = blockIdx.z;
    const int h0 = head * D_HEAD;

    bf16x8 aq[4];
    const int qrow = q0 + wave * 16 + l16;
#pragma unroll
    for (int ks = 0; ks < 4; ks++)
        aq[ks] = *(const bf16x8*)(Qg + (size_t)qrow * H_DIM + h0 + ks * 32 + quad * 8);

    unsigned short* myP = sP + wave * (16 * 72);

    const int k_r = wave * 4 + (lane >> 4);
    const int k_c = (lane & 15) ^ (k_r & 15);
    const int v_r = wave * 8 + (lane >> 3);
    const int v_c = (lane & 7) ^ (v_r & 7);

    const unsigned short* Kbase = Kg + h0;
    const unsigned short* Vbase = Vt + (size_t)h0 * S_LEN;
    const int kt0 = split * KV_PER;

    floatx4 z4 = {0.f, 0.f, 0.f, 0.f};
    floatx4 o[8];
#pragma unroll
    for (int i = 0; i < 8; i++) o[i] = z4;
    float l_r[4] = {0.f, 0.f, 0.f, 0.f};

#pragma unroll
    for (int it = 0; it < 4; it++) {
        dma16(sK0 + (wave * 4 + it * 16) * 128,
              Kbase + (size_t)(kt0 + k_r + it * 16) * H_DIM + k_c * 8);
        dma16(sV0 + (wave * 8 + it * 32) * 64,
              Vbase + (size_t)(v_r + it * 32) * S_LEN + kt0 + v_c * 8);
    }
    __syncthreads();

    int buf = 0;
    for (int it0 = 0; it0 < KV_PER; it0 += 64) {
        const int t0 = kt0 + it0;
        if (it0 + 64 < KV_PER) {
            const int nt = t0 + 64;
            unsigned short* nK = sK0 + (buf ^ 1) * 8192;
            unsigned short* nV = sV0 + (buf ^ 1) * 8192;
#pragma unroll
            for (int it = 0; it < 4; it++) {
                dma16(nK + (wave * 4 + it * 16) * 128,
                      Kbase + (size_t)(nt + k_r + it * 16) * H_DIM + k_c * 8);
                dma16(nV + (wave * 8 + it * 32) * 64,
                      Vbase + (size_t)(v_r + it * 32) * S_LEN + nt + v_c * 8);
            }
        }
        const unsigned short* cK = sK0 + buf * 8192;
        const unsigned short* cV = sV0 + buf * 8192;

        floatx4 sc[4];
#pragma unroll
        for (int ni = 0; ni < 4; ni++) {
            sc[ni] = z4;
#pragma unroll
            for (int ks = 0; ks < 4; ks++) {
                int p = (ks * 4 + quad) ^ l16;
                bf16x8 bk = *(const bf16x8*)(cK + (ni * 16 + l16) * 128 + p * 8);
                sc[ni] = __builtin_amdgcn_mfma_f32_16x16x32_bf16(aq[ks], bk, sc[ni], 0, 0, 0);
            }
        }

#pragma unroll
        for (int ni = 0; ni < 4; ni++)
#pragma unroll
            for (int r = 0; r < 4; r++) {
                float p = __expf(sc[ni][r] * 0.03125f);  // 1/sqrt(H)=1/32
                sc[ni][r] = p;
                l_r[r] += p;
            }

#pragma unroll
        for (int ni = 0; ni < 4; ni++)
#pragma unroll
            for (int r = 0; r < 4; r++) {
                int prow = quad * 4 + r;
                myP[prow * 72 + ((ni * 16 + l16) ^ ((prow & 8) << 1))] = f2b(sc[ni][r]);
            }
        bf16x8 ap[2];
#pragma unroll
        for (int ks = 0; ks < 2; ks++)
            ap[ks] = *(const bf16x8*)(myP + l16 * 72 + ((ks * 32 + quad * 8) ^ ((l16 & 8) << 1)));

#pragma unroll
        for (int ni = 0; ni < 8; ni++) {
#pragma unroll
            for (int ks = 0; ks < 2; ks++) {
                int p = (ks * 4 + quad) ^ (l16 & 7);
                bf16x8 bv = *(const bf16x8*)(cV + (ni * 16 + l16) * 64 + p * 8);
                o[ni] = __builtin_amdgcn_mfma_f32_16x16x32_bf16(ap[ks], bv, o[ni], 0, 0, 0);
            }
        }

        __syncthreads();  // drains next-tile DMA + fences reads of buf
        buf ^= 1;
    }

#pragma unroll
    for (int r = 0; r < 4; r++)
#pragma unroll
        for (int off = 1; off < 16; off <<= 1)
            l_r[r] += __shfl_xor(l_r[r], off, 64);

#pragma unroll
    for (int r = 0; r < 4; r++) {
        float inv = 1.0f / l_r[r];
        int row = q0 + wave * 16 + quad * 4 + r;
#pragma unroll
        for (int ni = 0; ni < 8; ni++)
            Op[((size_t)split * S_LEN + row) * H_DIM + h0 + ni * 16 + l16] =
                f2b(o[ni][r] * inv);
        if (l16 == 0)
            Lp[(split * NHEAD + head) * S_LEN + row] = l_r[r];
    }
}

// ---------------- merge KV-split partials + residual add + LayerNorm ----------------
__global__ __launch_bounds__(256) void merge_add_layernorm(
    const float* __restrict__ t, const unsigned short* __restrict__ Op,
    const float* __restrict__ Lp,
    float* __restrict__ of, unsigned short* __restrict__ ob)
{
    __shared__ float red[8];
    const int row = blockIdx.x, tid = threadIdx.x;
    const int head = tid >> 5;
    const size_t base = (size_t)row * H_DIM + tid * 4;

    float l_s[KSPLIT];
    ushort4 os[KSPLIT];
#pragma unroll
    for (int sp = 0; sp < KSPLIT; sp++) {
        os[sp] = *(const ushort4*)(Op + ((size_t)sp * S_LEN + row) * H_DIM + tid * 4);
        l_s[sp] = Lp[(sp * NHEAD + head) * S_LEN + row];
    }
    float W = 0.f, a0 = 0.f, a1 = 0.f, a2 = 0.f, a3 = 0.f;
#pragma unroll
    for (int sp = 0; sp < KSPLIT; sp++) {
        float w = l_s[sp];  // no-max softmax: weight is the raw partial sum
        W += w;
        a0 += w * b2f(os[sp].x);
        a1 += w * b2f(os[sp].y);
        a2 += w * b2f(os[sp].z);
        a3 += w * b2f(os[sp].w);
    }
    float inv = 1.0f / W;
    float4 x = *(const float4*)(t + base);
    float v0 = x.x + a0 * inv, v1 = x.y + a1 * inv;
    float v2 = x.z + a2 * inv, v3 = x.w + a3 * inv;

    float s = v0 + v1 + v2 + v3;
    float q = v0 * v0 + v1 * v1 + v2 * v2 + v3 * v3;
#pragma unroll
    for (int off = 32; off >= 1; off >>= 1) {
        s += __shfl_xor(s, off, 64);
        q += __shfl_xor(q, off, 64);
    }
    if ((tid & 63) == 0) { red[tid >> 6] = s; red[4 + (tid >> 6)] = q; }
    __syncthreads();
    s = red[0] + red[1] + red[2] + red[3];
    q = red[4] + red[5] + red[6] + red[7];
    const float mean = s * (1.0f / (float)H_DIM);
    const float var = q * (1.0f / (float)H_DIM) - mean * mean;
    const float rstd = rsqrtf(var + 1e-5f);
    float o0 = (v0 - mean) * rstd, o1 = (v1 - mean) * rstd;
    float o2 = (v2 - mean) * rstd, o3 = (v3 - mean) * rstd;
    *(float4*)(of + base) = make_float4(o0, o1, o2, o3);
    *(ushort4*)(ob + base) = make_ushort4(f2b(o0), f2b(o1), f2b(o2), f2b(o3));
}

// ---------------- fused residual add + LayerNorm (fp32 in -> fp32 + bf16 out) ----------------
__global__ __launch_bounds__(256) void add_layernorm(
    const float* __restrict__ a, const float* __restrict__ b,
    float* __restrict__ of, unsigned short* __restrict__ ob)
{
    __shared__ float red[8];
    const int row = blockIdx.x, tid = threadIdx.x;
    const size_t base = (size_t)row * H_DIM + tid * 4;
    float4 x = *(const float4*)(a + base);
    float4 y = *(const float4*)(b + base);
    float v0 = x.x + y.x, v1 = x.y + y.y, v2 = x.z + y.z, v3 = x.w + y.w;
    float s = v0 + v1 + v2 + v3;
    float q = v0 * v0 + v1 * v1 + v2 * v2 + v3 * v3;
#pragma unroll
    for (int off = 32; off >= 1; off >>= 1) {
        s += __shfl_xor(s, off, 64);
        q += __shfl_xor(q, off, 64);
    }
    if ((tid & 63) == 0) { red[tid >> 6] = s; red[4 + (tid >> 6)] = q; }
    __syncthreads();
    s = red[0] + red[1] + red[2] + red[3];
    q = red[4] + red[5] + red[6] + red[7];
    const float mean = s * (1.0f / (float)H_DIM);
    const float var = q * (1.0f / (float)H_DIM) - mean * mean;
    const float rstd = rsqrtf(var + 1e-5f);
    float o0 = (v0 - mean) * rstd, o1 = (v1 - mean) * rstd;
    float o2 = (v2 - mean) * rstd, o3 = (v3 - mean) * rstd;
    *(float4*)(of + base) = make_float4(o0, o1, o2, o3);
    *(ushort4*)(ob + base) = make_ushort4(f2b(o0), f2b(o1), f2b(o2), f2b(o3));
}

extern "C" void kernel_launch(void* const* d_in, const int* in_sizes, int n_in,
                              void* d_out, int out_size, void* d_ws, size_t ws_size,
                              hipStream_t stream)
{
    (void)in_sizes; (void)n_in; (void)out_size; (void)ws_size;
    const float* in = (const float*)d_in[0];
    const float* Wq = (const float*)d_in[1];
    const float* bq = (const float*)d_in[2];
    const float* Wk = (const float*)d_in[3];
    const float* bk = (const float*)d_in[4];
    const float* Wv = (const float*)d_in[5];
    const float* bv = (const float*)d_in[6];
    const float* W1 = (const float*)d_in[7];
    const float* b1 = (const float*)d_in[8];
    const float* W2 = (const float*)d_in[9];
    const float* b2 = (const float*)d_in[10];

    char* ws = (char*)d_ws;
    const size_t MB = 1024 * 1024;
    float* t_f32 = (float*)(ws + 0 * MB);                    // 8 MB
    float* cf_f32 = (float*)(ws + 8 * MB);                   // 8 MB (ff2)
    unsigned short* t_b = (unsigned short*)(ws + 16 * MB);   // 4 MB
    unsigned short* K_b = (unsigned short*)(ws + 20 * MB);   // 4 MB
    unsigned short* Vt_b = (unsigned short*)(ws + 24 * MB);  // 4 MB, [NH,D,S]
    unsigned short* Q_b = (unsigned short*)(ws + 28 * MB);   // 4 MB (also ff1)
    unsigned short* WqT = (unsigned short*)(ws + 32 * MB);   // 2 MB each, [N,K]
    unsigned short* WkT = (unsigned short*)(ws + 34 * MB);
    unsigned short* WvT = (unsigned short*)(ws + 36 * MB);
    unsigned short* W1T = (unsigned short*)(ws + 38 * MB);
    unsigned short* W2T = (unsigned short*)(ws + 40 * MB);
    unsigned short* Op = (unsigned short*)(ws + 42 * MB);    // 8 MB [split][S][H] bf16
    float* Lp = (float*)(ws + 58 * MB);                      // 128 KB [split][NH][S]

    // opt in to >64 KB / =64 KB dynamic LDS
    (void)hipFuncSetAttribute(reinterpret_cast<const void*>(&flash_attn),
                              hipFuncAttributeMaxDynamicSharedMemorySize, 74752);
    (void)hipFuncSetAttribute(reinterpret_cast<const void*>(&gemm128<0, false>),
                              hipFuncAttributeMaxDynamicSharedMemorySize, 65536);
    (void)hipFuncSetAttribute(reinterpret_cast<const void*>(&gemm128<0, true>),
                              hipFuncAttributeMaxDynamicSharedMemorySize, 65536);
    (void)hipFuncSetAttribute(reinterpret_cast<const void*>(&gemm128<2, false>),
                              hipFuncAttributeMaxDynamicSharedMemorySize, 65536);
    (void)hipFuncSetAttribute(reinterpret_cast<const void*>(&gemm_kv),
                              hipFuncAttributeMaxDynamicSharedMemorySize, 65536);

    transpose_all<<<dim3(4, 32, 40), dim3(32, 8), 0, stream>>>(
        Wq, Wk, Wv, W1, W2, WqT, WkT, WvT, W1T, W2T);

    posenc_kernel<<<(S_LEN * H_DIM) / 256, 256, 0, stream>>>(in, t_f32, t_b);

    dim3 gg(H_DIM / 128, S_LEN / 128);  // 8 x 16 = 128 blocks (wave=64x64)
    gemm_kv<<<dim3(8, 16, 2), 256, 65536, stream>>>(t_b, WkT, WvT, bk, bv, K_b, Vt_b);

    for (int layer = 0; layer < 6; layer++) {
        gemm128<0, false><<<gg, 256, 65536, stream>>>(t_b, WqT, bq, nullptr, Q_b, 0);
        flash_attn<<<dim3(S_LEN / 64, NHEAD, KSPLIT), 256, 74752, stream>>>(Q_b, K_b, Vt_b, Op, Lp);
        merge_add_layernorm<<<S_LEN, 256, 0, stream>>>(t_f32, Op, Lp, t_f32, t_b);
        gemm128<0, true><<<gg, 256, 65536, stream>>>(t_b, W1T, b1, nullptr, Q_b, 0);
        gemm128<2, false><<<gg, 256, 65536, stream>>>(Q_b, W2T, b2, cf_f32, nullptr, 0);
        float* of = (layer == 5) ? (float*)d_out : t_f32;
        add_layernorm<<<S_LEN, 256, 0, stream>>>(t_f32, cf_f32, of, t_b);
    }
}